// Round 7
// baseline (734.346 us; speedup 1.0000x reference)
//
#include <hip/hip_runtime.h>
#include <cstdint>
#include <math.h>

// ---------------------------------------------------------------------------
// ParallelAttention (GPT-NeoX style), MI355X gfx950.
//   SEQ=2048 BATCH=2 HID=2048 NH=16 HD=128, causal mask, RoPE full head dim.
// INTERFACE (established R0-R6):
//   * float inputs are FP32 (R1-4: reading as bf16 -> NaN patterns; R5/6 finite)
//   * OUTPUT is FP32 (R5==R6 bit-identical absmax 4.34 => both correct but
//     misread: bf16 u16 pairs read as fp32; doc: output follows reference
//     dtype = float32). This round writes fp32.
//   * inputs resolved by element count; w_dense = LAST 4194304 match.
// Pipeline:
//   rope_tab   : cos/sin tables [2048][64] f32 (ws, overlaps ctx region)
//   qkv_gemm   : hidden[4096x2048]f32 @ w_qkv^T f32 -> bf16 MFMA (RNE cast in
//                LDS staging) + bias + RoPE; Q,K -> [b][h][s][d] bf16;
//                V -> transposed [b][h][d][s] bf16
//   attn       : flash attention per (qtile=128, b, h); ctx bf16 [s][b][hd]
//   dense_gemm : ctx @ w_dense^T (f32 staged to bf16) -> d_out FP32
//   copy_bias  : b_dense f32 -> f32 output tail (skip_bias_add tuple elem)
// MFMA 16x16x32 bf16 layouts (verified m89/m91): A/B: row=lane&15,
//   k=(lane>>4)*8+j ; C/D: col=lane&15, row=(lane>>4)*4+reg.
// ---------------------------------------------------------------------------

typedef unsigned short u16;
typedef __bf16 bf16x8 __attribute__((ext_vector_type(8)));
typedef float floatx4 __attribute__((ext_vector_type(4)));

#define SEQ 2048
#define BATCH 2
#define HID 2048
#define NH 16
#define HD 128

__device__ __forceinline__ u16 f2bf(float f) {
  union { float f; uint32_t u; } v; v.f = f;
  uint32_t u = v.u;
  return (u16)((u + 0x7FFFu + ((u >> 16) & 1u)) >> 16);
}

// pack 8 fp32 -> 8 bf16 (RNE) and store 16B to LDS
__device__ __forceinline__ void st8_bf16(u16* dst, const float* s) {
  uint32_t pk[4];
#pragma unroll
  for (int j = 0; j < 4; j++)
    pk[j] = (uint32_t)f2bf(s[2 * j]) | ((uint32_t)f2bf(s[2 * j + 1]) << 16);
  *(uint4*)dst = make_uint4(pk[0], pk[1], pk[2], pk[3]);
}

// ---------------- cos/sin tables ----------------
__global__ void rope_tab(float* __restrict__ cosT, float* __restrict__ sinT) {
  int s = blockIdx.x;
  int i = threadIdx.x;  // 0..63
  float f = exp2f(-(float)i * (13.287712379549449f / 64.0f));  // 10000^(-i/64)
  float a = (float)s * f;
  float sv, cv;
  sincosf(a, &sv, &cv);
  cosT[s * 64 + i] = cv;
  sinT[s * 64 + i] = sv;
}

// ---------------- QKV GEMM + bias + RoPE (fp32 in, bf16 MFMA) ----------------
__global__ __launch_bounds__(256, 2) void qkv_gemm(
    const float* __restrict__ A, const float* __restrict__ W,
    const float* __restrict__ bias,
    const float* __restrict__ cosT, const float* __restrict__ sinT,
    u16* __restrict__ Qw, u16* __restrict__ Kw, u16* __restrict__ Vt) {
  __shared__ __align__(16) u16 As[128 * 64];
  __shared__ __align__(16) u16 Bs[128 * 64];
  const int tid = threadIdx.x;
  const int wv = tid >> 6, lane = tid & 63;
  const int quad = lane >> 4, l16 = lane & 15;
  const int bn = blockIdx.x, bm = blockIdx.y;
  const int rowA0 = bm * 128, rowB0 = bn * 128;
  const int wm = (wv >> 1) * 64;
  const int wn = (wv & 1) * 32;
  // n-tiles paired for RoPE: tile p (d in [0,64)) pairs with tile p+2 (d+64)
  const int ntoff[4] = {wn, wn + 16, wn + 64, wn + 80};

  floatx4 acc[4][4];
#pragma unroll
  for (int i = 0; i < 4; i++)
#pragma unroll
    for (int j = 0; j < 4; j++) acc[i][j] = (floatx4){0.f, 0.f, 0.f, 0.f};

  for (int kb = 0; kb < HID; kb += 64) {
    float fa[4][8], fb[4][8];
#pragma unroll
    for (int i = 0; i < 4; i++) {
      int c = i * 256 + tid;
      int row = c >> 3, k8 = (c & 7) * 8;
      const float* sa = &A[(size_t)(rowA0 + row) * HID + kb + k8];
      const float* sb = &W[(size_t)(rowB0 + row) * HID + kb + k8];
      *(floatx4*)&fa[i][0] = *(const floatx4*)sa;
      *(floatx4*)&fa[i][4] = *(const floatx4*)(sa + 4);
      *(floatx4*)&fb[i][0] = *(const floatx4*)sb;
      *(floatx4*)&fb[i][4] = *(const floatx4*)(sb + 4);
    }
    __syncthreads();
#pragma unroll
    for (int i = 0; i < 4; i++) {
      int c = i * 256 + tid;
      st8_bf16(&As[c * 8], fa[i]);
      st8_bf16(&Bs[c * 8], fb[i]);
    }
    __syncthreads();
#pragma unroll
    for (int ks = 0; ks < 64; ks += 32) {
      bf16x8 af[4], bfr[4];
#pragma unroll
      for (int mi = 0; mi < 4; mi++)
        af[mi] = *(const bf16x8*)&As[(wm + mi * 16 + l16) * 64 + ks + quad * 8];
#pragma unroll
      for (int ni = 0; ni < 4; ni++)
        bfr[ni] = *(const bf16x8*)&Bs[(ntoff[ni] + l16) * 64 + ks + quad * 8];
#pragma unroll
      for (int mi = 0; mi < 4; mi++)
#pragma unroll
        for (int ni = 0; ni < 4; ni++)
          acc[mi][ni] = __builtin_amdgcn_mfma_f32_16x16x32_bf16(
              af[mi], bfr[ni], acc[mi][ni], 0, 0, 0);
    }
    __syncthreads();
  }

  // epilogue: tile bn covers one 128-col segment: head = bn/3, seg = bn%3
  const int seg = bn % 3;
  const int head = bn / 3;
  float bv[4];
#pragma unroll
  for (int ni = 0; ni < 4; ni++)
    bv[ni] = bias[bn * 128 + ntoff[ni] + l16];

  if (seg < 2) {
    u16* dst = (seg == 0) ? Qw : Kw;
#pragma unroll
    for (int mi = 0; mi < 4; mi++) {
#pragma unroll
      for (int reg = 0; reg < 4; reg++) {
        int r = rowA0 + wm + mi * 16 + quad * 4 + reg;
        int s = r >> 1, b = r & 1;
        size_t base = ((size_t)(b * NH + head) * SEQ + s) * HD;
#pragma unroll
        for (int p = 0; p < 2; p++) {
          int dlo = ntoff[p] + l16;  // in [0,64)
          float lo = acc[mi][p][reg] + bv[p];
          float hi = acc[mi][p + 2][reg] + bv[p + 2];
          float cv = cosT[s * 64 + dlo];
          float sv = sinT[s * 64 + dlo];
          dst[base + dlo] = f2bf(lo * cv - hi * sv);
          dst[base + dlo + 64] = f2bf(hi * cv + lo * sv);
        }
      }
    }
  } else {
#pragma unroll
    for (int mi = 0; mi < 4; mi++) {
#pragma unroll
      for (int ni = 0; ni < 4; ni++) {
        int d = ntoff[ni] + l16;
#pragma unroll
        for (int reg = 0; reg < 4; reg++) {
          int r = rowA0 + wm + mi * 16 + quad * 4 + reg;
          int s = r >> 1, b = r & 1;
          Vt[((size_t)(b * NH + head) * HD + d) * SEQ + s] =
              f2bf(acc[mi][ni][reg] + bv[ni]);
        }
      }
    }
  }
}

// ---------------- flash attention (bf16 ws in, bf16 ctx out) ----------------
__global__ __launch_bounds__(256, 2) void attn(
    const u16* __restrict__ Qw, const u16* __restrict__ Kw,
    const u16* __restrict__ Vt, u16* __restrict__ ctx) {
  __shared__ __align__(16) u16 Ks[64 * 128];
  __shared__ __align__(16) u16 Vs[128 * 64];
  __shared__ __align__(16) u16 Pl[4 * 32 * 72];  // per-wave 32x64, stride 72

  const int tid = threadIdx.x;
  const int wv = tid >> 6, lane = tid & 63;
  const int quad = lane >> 4, l16 = lane & 15;
  const int bh = blockIdx.y;
  const int b = bh >> 4, h = bh & 15;
  const int qt = (gridDim.x - 1) - blockIdx.x;  // longest blocks first
  const int sw = qt * 128 + wv * 32;            // this wave's 32 q-rows
  const size_t bhoff = (size_t)bh * SEQ * HD;

  bf16x8 qf[2][4];
#pragma unroll
  for (int mi = 0; mi < 2; mi++)
#pragma unroll
    for (int kc = 0; kc < 4; kc++)
      qf[mi][kc] = *(const bf16x8*)&Qw[bhoff +
                                       (size_t)(sw + mi * 16 + l16) * HD +
                                       kc * 32 + quad * 8];

  floatx4 o[2][8];
#pragma unroll
  for (int mi = 0; mi < 2; mi++)
#pragma unroll
    for (int ni = 0; ni < 8; ni++) o[mi][ni] = (floatx4){0.f, 0.f, 0.f, 0.f};
  float mst[2][4], lst[2][4];
#pragma unroll
  for (int mi = 0; mi < 2; mi++)
#pragma unroll
    for (int r = 0; r < 4; r++) { mst[mi][r] = -1e30f; lst[mi][r] = 0.f; }

  const int nt = qt * 2 + 2;
  const float inv_norm = 0.088388347648318447f;  // 1/sqrt(128)

  for (int t = 0; t < nt; t++) {
    bf16x8 tk[4], tv[4];
#pragma unroll
    for (int i = 0; i < 4; i++) {
      int c = i * 256 + tid;
      tk[i] = *(const bf16x8*)&Kw[bhoff + (size_t)(t * 64 + (c >> 4)) * HD +
                                  (c & 15) * 8];
      tv[i] = *(const bf16x8*)&Vt[bhoff + (size_t)(c >> 3) * SEQ + t * 64 +
                                  (c & 7) * 8];
    }
    __syncthreads();
#pragma unroll
    for (int i = 0; i < 4; i++) {
      int c = i * 256 + tid;
      *(bf16x8*)&Ks[c * 8] = tk[i];
      *(bf16x8*)&Vs[c * 8] = tv[i];
    }
    __syncthreads();

    const bool active = (t * 64 <= sw + 31);
    if (active) {
      floatx4 sa[2][4];
#pragma unroll
      for (int mi = 0; mi < 2; mi++)
#pragma unroll
        for (int ni = 0; ni < 4; ni++) sa[mi][ni] = (floatx4){0.f, 0.f, 0.f, 0.f};
#pragma unroll
      for (int kc = 0; kc < 4; kc++) {
        bf16x8 kf[4];
#pragma unroll
        for (int ni = 0; ni < 4; ni++)
          kf[ni] = *(const bf16x8*)&Ks[(ni * 16 + l16) * 128 + kc * 32 + quad * 8];
#pragma unroll
        for (int mi = 0; mi < 2; mi++)
#pragma unroll
          for (int ni = 0; ni < 4; ni++)
            sa[mi][ni] = __builtin_amdgcn_mfma_f32_16x16x32_bf16(
                qf[mi][kc], kf[ni], sa[mi][ni], 0, 0, 0);
      }
      // online softmax per row (row = quad*4+reg, replicated across 16 lanes)
      float alpha[2][4];
#pragma unroll
      for (int mi = 0; mi < 2; mi++) {
#pragma unroll
        for (int reg = 0; reg < 4; reg++) {
          int sq = sw + mi * 16 + quad * 4 + reg;
          float rv[4];
#pragma unroll
          for (int ni = 0; ni < 4; ni++) {
            int sk = t * 64 + ni * 16 + l16;
            float v = sa[mi][ni][reg] * inv_norm;
            if (sk > sq) v = -10000.0f;  // exact reference mask value
            rv[ni] = v;
          }
          float rmax = fmaxf(fmaxf(rv[0], rv[1]), fmaxf(rv[2], rv[3]));
          rmax = fmaxf(rmax, __shfl_xor(rmax, 1));
          rmax = fmaxf(rmax, __shfl_xor(rmax, 2));
          rmax = fmaxf(rmax, __shfl_xor(rmax, 4));
          rmax = fmaxf(rmax, __shfl_xor(rmax, 8));
          float mn = fmaxf(mst[mi][reg], rmax);
          float al = expf(mst[mi][reg] - mn);
          float rs = 0.f;
#pragma unroll
          for (int ni = 0; ni < 4; ni++) {
            float p = expf(rv[ni] - mn);
            rs += p;
            Pl[wv * 2304 + (mi * 16 + quad * 4 + reg) * 72 + ni * 16 + l16] =
                f2bf(p);
          }
          rs += __shfl_xor(rs, 1);
          rs += __shfl_xor(rs, 2);
          rs += __shfl_xor(rs, 4);
          rs += __shfl_xor(rs, 8);
          lst[mi][reg] = lst[mi][reg] * al + rs;
          mst[mi][reg] = mn;
          alpha[mi][reg] = al;
        }
      }
#pragma unroll
      for (int mi = 0; mi < 2; mi++)
#pragma unroll
        for (int ni = 0; ni < 8; ni++)
#pragma unroll
          for (int reg = 0; reg < 4; reg++)
            o[mi][ni][reg] *= alpha[mi][reg];
    }
    __syncthreads();  // convergent; orders P write -> P read, Ks/Vs reuse
    if (active) {
#pragma unroll
      for (int kc = 0; kc < 2; kc++) {
        bf16x8 pf[2];
#pragma unroll
        for (int mi = 0; mi < 2; mi++)
          pf[mi] = *(const bf16x8*)&Pl[wv * 2304 + (mi * 16 + l16) * 72 +
                                       kc * 32 + quad * 8];
#pragma unroll
        for (int ni = 0; ni < 8; ni++) {
          bf16x8 vf =
              *(const bf16x8*)&Vs[(ni * 16 + l16) * 64 + kc * 32 + quad * 8];
#pragma unroll
          for (int mi = 0; mi < 2; mi++)
            o[mi][ni] = __builtin_amdgcn_mfma_f32_16x16x32_bf16(
                pf[mi], vf, o[mi][ni], 0, 0, 0);
        }
      }
    }
  }

  // final 1/l and store ctx [s][b][h*128+d]
#pragma unroll
  for (int mi = 0; mi < 2; mi++) {
#pragma unroll
    for (int reg = 0; reg < 4; reg++) {
      float inv = 1.0f / lst[mi][reg];
      int sq = sw + mi * 16 + quad * 4 + reg;
      size_t rbase = ((size_t)(sq * BATCH + b)) * HID + h * HD;
#pragma unroll
      for (int ni = 0; ni < 8; ni++)
        ctx[rbase + ni * 16 + l16] = f2bf(o[mi][ni][reg] * inv);
    }
  }
}

// ---------- dense GEMM (ctx bf16 @ w_dense^T fp32, no bias) -> FP32 out ----------
__global__ __launch_bounds__(256, 2) void dense_gemm(
    const u16* __restrict__ A, const float* __restrict__ W,
    float* __restrict__ out) {
  __shared__ __align__(16) u16 As[128 * 64];
  __shared__ __align__(16) u16 Bs[128 * 64];
  const int tid = threadIdx.x;
  const int wv = tid >> 6, lane = tid & 63;
  const int quad = lane >> 4, l16 = lane & 15;
  const int bn = blockIdx.x, bm = blockIdx.y;
  const int rowA0 = bm * 128, rowB0 = bn * 128;
  const int wm = (wv >> 1) * 64;
  const int wn = (wv & 1) * 64;
  const int ntoff[4] = {wn, wn + 16, wn + 32, wn + 48};

  floatx4 acc[4][4];
#pragma unroll
  for (int i = 0; i < 4; i++)
#pragma unroll
    for (int j = 0; j < 4; j++) acc[i][j] = (floatx4){0.f, 0.f, 0.f, 0.f};

  for (int kb = 0; kb < HID; kb += 64) {
    bf16x8 ta[4];
    float fb[4][8];
#pragma unroll
    for (int i = 0; i < 4; i++) {
      int c = i * 256 + tid;
      int row = c >> 3, k8 = (c & 7) * 8;
      ta[i] = *(const bf16x8*)&A[(size_t)(rowA0 + row) * HID + kb + k8];
      const float* sb = &W[(size_t)(rowB0 + row) * HID + kb + k8];
      *(floatx4*)&fb[i][0] = *(const floatx4*)sb;
      *(floatx4*)&fb[i][4] = *(const floatx4*)(sb + 4);
    }
    __syncthreads();
#pragma unroll
    for (int i = 0; i < 4; i++) {
      int c = i * 256 + tid;
      *(bf16x8*)&As[c * 8] = ta[i];
      st8_bf16(&Bs[c * 8], fb[i]);
    }
    __syncthreads();
#pragma unroll
    for (int ks = 0; ks < 64; ks += 32) {
      bf16x8 af[4], bfr[4];
#pragma unroll
      for (int mi = 0; mi < 4; mi++)
        af[mi] = *(const bf16x8*)&As[(wm + mi * 16 + l16) * 64 + ks + quad * 8];
#pragma unroll
      for (int ni = 0; ni < 4; ni++)
        bfr[ni] = *(const bf16x8*)&Bs[(ntoff[ni] + l16) * 64 + ks + quad * 8];
#pragma unroll
      for (int mi = 0; mi < 4; mi++)
#pragma unroll
        for (int ni = 0; ni < 4; ni++)
          acc[mi][ni] = __builtin_amdgcn_mfma_f32_16x16x32_bf16(
              af[mi], bfr[ni], acc[mi][ni], 0, 0, 0);
    }
    __syncthreads();
  }

#pragma unroll
  for (int mi = 0; mi < 4; mi++)
#pragma unroll
    for (int reg = 0; reg < 4; reg++) {
      int r = rowA0 + wm + mi * 16 + quad * 4 + reg;
#pragma unroll
      for (int ni = 0; ni < 4; ni++)
        out[(size_t)r * HID + bn * 128 + ntoff[ni] + l16] = acc[mi][ni][reg];
    }
}

// ---------------- bias passthrough (fp32 in -> fp32 out tail) ----------------
__global__ void copy_bias(const float* __restrict__ bd, float* __restrict__ out) {
  int i = blockIdx.x * 256 + threadIdx.x;
  if (i < HID) out[(size_t)SEQ * BATCH * HID + i] = bd[i];
}

extern "C" void kernel_launch(void* const* d_in, const int* in_sizes, int n_in,
                              void* d_out, int out_size, void* d_ws,
                              size_t ws_size, hipStream_t stream) {
  // Resolve inputs BY ELEMENT COUNT (dtype-independent):
  //   hidden 8388608, mask 4194304 (unused, precedes w_dense), w_qkv 12582912,
  //   b_qkv 6144, w_dense 4194304 (LAST match wins), b_dense 2048.
  const float *hidden = nullptr, *w_qkv = nullptr, *b_qkv = nullptr;
  const float *w_dense = nullptr, *b_dense = nullptr;
  for (int i = 0; i < n_in; i++) {
    long s = in_sizes[i];
    if (s == 8388608L) hidden = (const float*)d_in[i];
    else if (s == 12582912L) w_qkv = (const float*)d_in[i];
    else if (s == 6144L) b_qkv = (const float*)d_in[i];
    else if (s == 4194304L) w_dense = (const float*)d_in[i];  // last wins
    else if (s == 2048L) b_dense = (const float*)d_in[i];
  }
  float* out = (float*)d_out;

  // Workspace: 64 MB. Rope tables overlap ctx (dead before attn writes ctx).
  char* ws = (char*)d_ws;
  u16* Qw = (u16*)(ws);                     // [ 0,16M)
  u16* Kw = (u16*)(ws + 16777216ll);        // [16,32M)
  u16* Vt = (u16*)(ws + 33554432ll);        // [32,48M)
  u16* ctx = (u16*)(ws + 50331648ll);       // [48,64M)
  float* cosT = (float*)(ws + 50331648ll);  // first 512K of ctx region
  float* sinT = (float*)(ws + 50331648ll + 524288ll);

  rope_tab<<<dim3(2048), dim3(64), 0, stream>>>(cosT, sinT);
  qkv_gemm<<<dim3(48, 32), dim3(256), 0, stream>>>(hidden, w_qkv, b_qkv, cosT,
                                                   sinT, Qw, Kw, Vt);
  attn<<<dim3(16, 32), dim3(256), 0, stream>>>(Qw, Kw, Vt, ctx);
  dense_gemm<<<dim3(16, 32), dim3(256), 0, stream>>>(ctx, w_dense, out);
  copy_bias<<<dim3(8), dim3(256), 0, stream>>>(b_dense, out);
}

// Round 8
// 614.358 us; speedup vs baseline: 1.1953x; 1.1953x over previous
//
#include <hip/hip_runtime.h>
#include <cstdint>
#include <math.h>

// ---------------------------------------------------------------------------
// ParallelAttention (GPT-NeoX style), MI355X gfx950.
//   SEQ=2048 BATCH=2 HID=2048 NH=16 HD=128, causal mask, RoPE full head dim.
// INTERFACE (established R0-R7): fp32 inputs, fp32 output, inputs resolved by
//   element count (w_dense = LAST 4194304 match; mask unused).
// R8: LDS row strides padded (64->72, 128->136) to kill the 16-way
//   ds_read_b128 bank conflicts (R7: SQ_LDS_BANK_CONFLICT=3.8e7, MfmaUtil
//   12.4% -- per m136, 16-way = 5.7x LDS slowdown; 2-way residual is free).
// Pipeline:
//   rope_tab   : cos/sin tables [2048][64] f32 (ws, overlaps ctx region)
//   qkv_gemm   : hidden f32 @ w_qkv^T f32 -> bf16 MFMA (RNE cast in staging)
//                + bias + RoPE; Q,K -> [b][h][s][d]; V -> [b][h][d][s]
//   attn       : flash attention per (qtile=128, b, h); ctx bf16 [s][b][hd]
//   dense_gemm : ctx @ w_dense^T (f32 staged to bf16) -> d_out FP32
//   copy_bias  : b_dense f32 -> f32 output tail
// MFMA 16x16x32 bf16: A/B row=lane&15, k=(lane>>4)*8+j; C/D col=lane&15,
//   row=(lane>>4)*4+reg (verified m89/m91).
// ---------------------------------------------------------------------------

typedef unsigned short u16;
typedef __bf16 bf16x8 __attribute__((ext_vector_type(8)));
typedef float floatx4 __attribute__((ext_vector_type(4)));

#define SEQ 2048
#define BATCH 2
#define HID 2048
#define NH 16
#define HD 128
#define LDA 72    // padded row stride for 64-wide tiles (36 dwords = 4 mod 32)
#define LDK 136   // padded row stride for 128-wide K tile (68 dwords = 4 mod 32)

__device__ __forceinline__ u16 f2bf(float f) {
  union { float f; uint32_t u; } v; v.f = f;
  uint32_t u = v.u;
  return (u16)((u + 0x7FFFu + ((u >> 16) & 1u)) >> 16);
}

// pack 8 fp32 -> 8 bf16 (RNE) and store 16B to LDS
__device__ __forceinline__ void st8_bf16(u16* dst, const float* s) {
  uint32_t pk[4];
#pragma unroll
  for (int j = 0; j < 4; j++)
    pk[j] = (uint32_t)f2bf(s[2 * j]) | ((uint32_t)f2bf(s[2 * j + 1]) << 16);
  *(uint4*)dst = make_uint4(pk[0], pk[1], pk[2], pk[3]);
}

// ---------------- cos/sin tables ----------------
__global__ void rope_tab(float* __restrict__ cosT, float* __restrict__ sinT) {
  int s = blockIdx.x;
  int i = threadIdx.x;  // 0..63
  float f = exp2f(-(float)i * (13.287712379549449f / 64.0f));  // 10000^(-i/64)
  float a = (float)s * f;
  float sv, cv;
  sincosf(a, &sv, &cv);
  cosT[s * 64 + i] = cv;
  sinT[s * 64 + i] = sv;
}

// ---------------- QKV GEMM + bias + RoPE (fp32 in, bf16 MFMA) ----------------
__global__ __launch_bounds__(256, 2) void qkv_gemm(
    const float* __restrict__ A, const float* __restrict__ W,
    const float* __restrict__ bias,
    const float* __restrict__ cosT, const float* __restrict__ sinT,
    u16* __restrict__ Qw, u16* __restrict__ Kw, u16* __restrict__ Vt) {
  __shared__ __align__(16) u16 As[128 * LDA];
  __shared__ __align__(16) u16 Bs[128 * LDA];
  const int tid = threadIdx.x;
  const int wv = tid >> 6, lane = tid & 63;
  const int quad = lane >> 4, l16 = lane & 15;
  const int bn = blockIdx.x, bm = blockIdx.y;
  const int rowA0 = bm * 128, rowB0 = bn * 128;
  const int wm = (wv >> 1) * 64;
  const int wn = (wv & 1) * 32;
  // n-tiles paired for RoPE: tile p (d in [0,64)) pairs with tile p+2 (d+64)
  const int ntoff[4] = {wn, wn + 16, wn + 64, wn + 80};

  floatx4 acc[4][4];
#pragma unroll
  for (int i = 0; i < 4; i++)
#pragma unroll
    for (int j = 0; j < 4; j++) acc[i][j] = (floatx4){0.f, 0.f, 0.f, 0.f};

  for (int kb = 0; kb < HID; kb += 64) {
    float fa[4][8], fb[4][8];
#pragma unroll
    for (int i = 0; i < 4; i++) {
      int c = i * 256 + tid;
      int row = c >> 3, k8 = (c & 7) * 8;
      const float* sa = &A[(size_t)(rowA0 + row) * HID + kb + k8];
      const float* sb = &W[(size_t)(rowB0 + row) * HID + kb + k8];
      *(floatx4*)&fa[i][0] = *(const floatx4*)sa;
      *(floatx4*)&fa[i][4] = *(const floatx4*)(sa + 4);
      *(floatx4*)&fb[i][0] = *(const floatx4*)sb;
      *(floatx4*)&fb[i][4] = *(const floatx4*)(sb + 4);
    }
    __syncthreads();
#pragma unroll
    for (int i = 0; i < 4; i++) {
      int c = i * 256 + tid;
      int row = c >> 3, k8 = (c & 7) * 8;
      st8_bf16(&As[row * LDA + k8], fa[i]);
      st8_bf16(&Bs[row * LDA + k8], fb[i]);
    }
    __syncthreads();
#pragma unroll
    for (int ks = 0; ks < 64; ks += 32) {
      bf16x8 af[4], bfr[4];
#pragma unroll
      for (int mi = 0; mi < 4; mi++)
        af[mi] = *(const bf16x8*)&As[(wm + mi * 16 + l16) * LDA + ks + quad * 8];
#pragma unroll
      for (int ni = 0; ni < 4; ni++)
        bfr[ni] = *(const bf16x8*)&Bs[(ntoff[ni] + l16) * LDA + ks + quad * 8];
#pragma unroll
      for (int mi = 0; mi < 4; mi++)
#pragma unroll
        for (int ni = 0; ni < 4; ni++)
          acc[mi][ni] = __builtin_amdgcn_mfma_f32_16x16x32_bf16(
              af[mi], bfr[ni], acc[mi][ni], 0, 0, 0);
    }
    __syncthreads();
  }

  // epilogue: tile bn covers one 128-col segment: head = bn/3, seg = bn%3
  const int seg = bn % 3;
  const int head = bn / 3;
  float bv[4];
#pragma unroll
  for (int ni = 0; ni < 4; ni++)
    bv[ni] = bias[bn * 128 + ntoff[ni] + l16];

  if (seg < 2) {
    u16* dst = (seg == 0) ? Qw : Kw;
#pragma unroll
    for (int mi = 0; mi < 4; mi++) {
#pragma unroll
      for (int reg = 0; reg < 4; reg++) {
        int r = rowA0 + wm + mi * 16 + quad * 4 + reg;
        int s = r >> 1, b = r & 1;
        size_t base = ((size_t)(b * NH + head) * SEQ + s) * HD;
#pragma unroll
        for (int p = 0; p < 2; p++) {
          int dlo = ntoff[p] + l16;  // in [0,64)
          float lo = acc[mi][p][reg] + bv[p];
          float hi = acc[mi][p + 2][reg] + bv[p + 2];
          float cv = cosT[s * 64 + dlo];
          float sv = sinT[s * 64 + dlo];
          dst[base + dlo] = f2bf(lo * cv - hi * sv);
          dst[base + dlo + 64] = f2bf(hi * cv + lo * sv);
        }
      }
    }
  } else {
#pragma unroll
    for (int mi = 0; mi < 4; mi++) {
#pragma unroll
      for (int ni = 0; ni < 4; ni++) {
        int d = ntoff[ni] + l16;
#pragma unroll
        for (int reg = 0; reg < 4; reg++) {
          int r = rowA0 + wm + mi * 16 + quad * 4 + reg;
          int s = r >> 1, b = r & 1;
          Vt[((size_t)(b * NH + head) * HD + d) * SEQ + s] =
              f2bf(acc[mi][ni][reg] + bv[ni]);
        }
      }
    }
  }
}

// ---------------- flash attention (bf16 ws in, bf16 ctx out) ----------------
__global__ __launch_bounds__(256, 2) void attn(
    const u16* __restrict__ Qw, const u16* __restrict__ Kw,
    const u16* __restrict__ Vt, u16* __restrict__ ctx) {
  __shared__ __align__(16) u16 Ks[64 * LDK];
  __shared__ __align__(16) u16 Vs[128 * LDA];
  __shared__ __align__(16) u16 Pl[4 * 32 * 72];  // per-wave 32x64, stride 72

  const int tid = threadIdx.x;
  const int wv = tid >> 6, lane = tid & 63;
  const int quad = lane >> 4, l16 = lane & 15;
  const int bh = blockIdx.y;
  const int b = bh >> 4, h = bh & 15;
  const int qt = (gridDim.x - 1) - blockIdx.x;  // longest blocks first
  const int sw = qt * 128 + wv * 32;            // this wave's 32 q-rows
  const size_t bhoff = (size_t)bh * SEQ * HD;

  bf16x8 qf[2][4];
#pragma unroll
  for (int mi = 0; mi < 2; mi++)
#pragma unroll
    for (int kc = 0; kc < 4; kc++)
      qf[mi][kc] = *(const bf16x8*)&Qw[bhoff +
                                       (size_t)(sw + mi * 16 + l16) * HD +
                                       kc * 32 + quad * 8];

  floatx4 o[2][8];
#pragma unroll
  for (int mi = 0; mi < 2; mi++)
#pragma unroll
    for (int ni = 0; ni < 8; ni++) o[mi][ni] = (floatx4){0.f, 0.f, 0.f, 0.f};
  float mst[2][4], lst[2][4];
#pragma unroll
  for (int mi = 0; mi < 2; mi++)
#pragma unroll
    for (int r = 0; r < 4; r++) { mst[mi][r] = -1e30f; lst[mi][r] = 0.f; }

  const int nt = qt * 2 + 2;
  const float inv_norm = 0.088388347648318447f;  // 1/sqrt(128)

  for (int t = 0; t < nt; t++) {
    bf16x8 tk[4], tv[4];
#pragma unroll
    for (int i = 0; i < 4; i++) {
      int c = i * 256 + tid;
      tk[i] = *(const bf16x8*)&Kw[bhoff + (size_t)(t * 64 + (c >> 4)) * HD +
                                  (c & 15) * 8];
      tv[i] = *(const bf16x8*)&Vt[bhoff + (size_t)(c >> 3) * SEQ + t * 64 +
                                  (c & 7) * 8];
    }
    __syncthreads();
#pragma unroll
    for (int i = 0; i < 4; i++) {
      int c = i * 256 + tid;
      *(bf16x8*)&Ks[(c >> 4) * LDK + (c & 15) * 8] = tk[i];
      *(bf16x8*)&Vs[(c >> 3) * LDA + (c & 7) * 8] = tv[i];
    }
    __syncthreads();

    const bool active = (t * 64 <= sw + 31);
    if (active) {
      floatx4 sa[2][4];
#pragma unroll
      for (int mi = 0; mi < 2; mi++)
#pragma unroll
        for (int ni = 0; ni < 4; ni++) sa[mi][ni] = (floatx4){0.f, 0.f, 0.f, 0.f};
#pragma unroll
      for (int kc = 0; kc < 4; kc++) {
        bf16x8 kf[4];
#pragma unroll
        for (int ni = 0; ni < 4; ni++)
          kf[ni] = *(const bf16x8*)&Ks[(ni * 16 + l16) * LDK + kc * 32 + quad * 8];
#pragma unroll
        for (int mi = 0; mi < 2; mi++)
#pragma unroll
          for (int ni = 0; ni < 4; ni++)
            sa[mi][ni] = __builtin_amdgcn_mfma_f32_16x16x32_bf16(
                qf[mi][kc], kf[ni], sa[mi][ni], 0, 0, 0);
      }
      // online softmax per row (row = quad*4+reg, replicated across 16 lanes)
      float alpha[2][4];
#pragma unroll
      for (int mi = 0; mi < 2; mi++) {
#pragma unroll
        for (int reg = 0; reg < 4; reg++) {
          int sq = sw + mi * 16 + quad * 4 + reg;
          float rv[4];
#pragma unroll
          for (int ni = 0; ni < 4; ni++) {
            int sk = t * 64 + ni * 16 + l16;
            float v = sa[mi][ni][reg] * inv_norm;
            if (sk > sq) v = -10000.0f;  // exact reference mask value
            rv[ni] = v;
          }
          float rmax = fmaxf(fmaxf(rv[0], rv[1]), fmaxf(rv[2], rv[3]));
          rmax = fmaxf(rmax, __shfl_xor(rmax, 1));
          rmax = fmaxf(rmax, __shfl_xor(rmax, 2));
          rmax = fmaxf(rmax, __shfl_xor(rmax, 4));
          rmax = fmaxf(rmax, __shfl_xor(rmax, 8));
          float mn = fmaxf(mst[mi][reg], rmax);
          float al = expf(mst[mi][reg] - mn);
          float rs = 0.f;
#pragma unroll
          for (int ni = 0; ni < 4; ni++) {
            float p = expf(rv[ni] - mn);
            rs += p;
            Pl[wv * 2304 + (mi * 16 + quad * 4 + reg) * 72 + ni * 16 + l16] =
                f2bf(p);
          }
          rs += __shfl_xor(rs, 1);
          rs += __shfl_xor(rs, 2);
          rs += __shfl_xor(rs, 4);
          rs += __shfl_xor(rs, 8);
          lst[mi][reg] = lst[mi][reg] * al + rs;
          mst[mi][reg] = mn;
          alpha[mi][reg] = al;
        }
      }
#pragma unroll
      for (int mi = 0; mi < 2; mi++)
#pragma unroll
        for (int ni = 0; ni < 8; ni++)
#pragma unroll
          for (int reg = 0; reg < 4; reg++)
            o[mi][ni][reg] *= alpha[mi][reg];
    }
    __syncthreads();  // convergent; orders P write -> P read, Ks/Vs reuse
    if (active) {
#pragma unroll
      for (int kc = 0; kc < 2; kc++) {
        bf16x8 pf[2];
#pragma unroll
        for (int mi = 0; mi < 2; mi++)
          pf[mi] = *(const bf16x8*)&Pl[wv * 2304 + (mi * 16 + l16) * 72 +
                                       kc * 32 + quad * 8];
#pragma unroll
        for (int ni = 0; ni < 8; ni++) {
          bf16x8 vf =
              *(const bf16x8*)&Vs[(ni * 16 + l16) * LDA + kc * 32 + quad * 8];
#pragma unroll
          for (int mi = 0; mi < 2; mi++)
            o[mi][ni] = __builtin_amdgcn_mfma_f32_16x16x32_bf16(
                pf[mi], vf, o[mi][ni], 0, 0, 0);
        }
      }
    }
  }

  // final 1/l and store ctx [s][b][h*128+d]
#pragma unroll
  for (int mi = 0; mi < 2; mi++) {
#pragma unroll
    for (int reg = 0; reg < 4; reg++) {
      float inv = 1.0f / lst[mi][reg];
      int sq = sw + mi * 16 + quad * 4 + reg;
      size_t rbase = ((size_t)(sq * BATCH + b)) * HID + h * HD;
#pragma unroll
      for (int ni = 0; ni < 8; ni++)
        ctx[rbase + ni * 16 + l16] = f2bf(o[mi][ni][reg] * inv);
    }
  }
}

// ---------- dense GEMM (ctx bf16 @ w_dense^T fp32, no bias) -> FP32 out ----------
__global__ __launch_bounds__(256, 2) void dense_gemm(
    const u16* __restrict__ A, const float* __restrict__ W,
    float* __restrict__ out) {
  __shared__ __align__(16) u16 As[128 * LDA];
  __shared__ __align__(16) u16 Bs[128 * LDA];
  const int tid = threadIdx.x;
  const int wv = tid >> 6, lane = tid & 63;
  const int quad = lane >> 4, l16 = lane & 15;
  const int bn = blockIdx.x, bm = blockIdx.y;
  const int rowA0 = bm * 128, rowB0 = bn * 128;
  const int wm = (wv >> 1) * 64;
  const int wn = (wv & 1) * 64;
  const int ntoff[4] = {wn, wn + 16, wn + 32, wn + 48};

  floatx4 acc[4][4];
#pragma unroll
  for (int i = 0; i < 4; i++)
#pragma unroll
    for (int j = 0; j < 4; j++) acc[i][j] = (floatx4){0.f, 0.f, 0.f, 0.f};

  for (int kb = 0; kb < HID; kb += 64) {
    bf16x8 ta[4];
    float fb[4][8];
#pragma unroll
    for (int i = 0; i < 4; i++) {
      int c = i * 256 + tid;
      int row = c >> 3, k8 = (c & 7) * 8;
      ta[i] = *(const bf16x8*)&A[(size_t)(rowA0 + row) * HID + kb + k8];
      const float* sb = &W[(size_t)(rowB0 + row) * HID + kb + k8];
      *(floatx4*)&fb[i][0] = *(const floatx4*)sb;
      *(floatx4*)&fb[i][4] = *(const floatx4*)(sb + 4);
    }
    __syncthreads();
#pragma unroll
    for (int i = 0; i < 4; i++) {
      int c = i * 256 + tid;
      int row = c >> 3, k8 = (c & 7) * 8;
      *(bf16x8*)&As[row * LDA + k8] = ta[i];
      st8_bf16(&Bs[row * LDA + k8], fb[i]);
    }
    __syncthreads();
#pragma unroll
    for (int ks = 0; ks < 64; ks += 32) {
      bf16x8 af[4], bfr[4];
#pragma unroll
      for (int mi = 0; mi < 4; mi++)
        af[mi] = *(const bf16x8*)&As[(wm + mi * 16 + l16) * LDA + ks + quad * 8];
#pragma unroll
      for (int ni = 0; ni < 4; ni++)
        bfr[ni] = *(const bf16x8*)&Bs[(ntoff[ni] + l16) * LDA + ks + quad * 8];
#pragma unroll
      for (int mi = 0; mi < 4; mi++)
#pragma unroll
        for (int ni = 0; ni < 4; ni++)
          acc[mi][ni] = __builtin_amdgcn_mfma_f32_16x16x32_bf16(
              af[mi], bfr[ni], acc[mi][ni], 0, 0, 0);
    }
    __syncthreads();
  }

#pragma unroll
  for (int mi = 0; mi < 4; mi++)
#pragma unroll
    for (int reg = 0; reg < 4; reg++) {
      int r = rowA0 + wm + mi * 16 + quad * 4 + reg;
#pragma unroll
      for (int ni = 0; ni < 4; ni++)
        out[(size_t)r * HID + bn * 128 + ntoff[ni] + l16] = acc[mi][ni][reg];
    }
}

// ---------------- bias passthrough (fp32 in -> fp32 out tail) ----------------
__global__ void copy_bias(const float* __restrict__ bd, float* __restrict__ out) {
  int i = blockIdx.x * 256 + threadIdx.x;
  if (i < HID) out[(size_t)SEQ * BATCH * HID + i] = bd[i];
}

extern "C" void kernel_launch(void* const* d_in, const int* in_sizes, int n_in,
                              void* d_out, int out_size, void* d_ws,
                              size_t ws_size, hipStream_t stream) {
  // Resolve inputs BY ELEMENT COUNT (dtype-independent):
  //   hidden 8388608, mask 4194304 (unused, precedes w_dense), w_qkv 12582912,
  //   b_qkv 6144, w_dense 4194304 (LAST match wins), b_dense 2048.
  const float *hidden = nullptr, *w_qkv = nullptr, *b_qkv = nullptr;
  const float *w_dense = nullptr, *b_dense = nullptr;
  for (int i = 0; i < n_in; i++) {
    long s = in_sizes[i];
    if (s == 8388608L) hidden = (const float*)d_in[i];
    else if (s == 12582912L) w_qkv = (const float*)d_in[i];
    else if (s == 6144L) b_qkv = (const float*)d_in[i];
    else if (s == 4194304L) w_dense = (const float*)d_in[i];  // last wins
    else if (s == 2048L) b_dense = (const float*)d_in[i];
  }
  float* out = (float*)d_out;

  // Workspace: 64 MB. Rope tables overlap ctx (dead before attn writes ctx).
  char* ws = (char*)d_ws;
  u16* Qw = (u16*)(ws);                     // [ 0,16M)
  u16* Kw = (u16*)(ws + 16777216ll);        // [16,32M)
  u16* Vt = (u16*)(ws + 33554432ll);        // [32,48M)
  u16* ctx = (u16*)(ws + 50331648ll);       // [48,64M)
  float* cosT = (float*)(ws + 50331648ll);  // first 512K of ctx region
  float* sinT = (float*)(ws + 50331648ll + 524288ll);

  rope_tab<<<dim3(2048), dim3(64), 0, stream>>>(cosT, sinT);
  qkv_gemm<<<dim3(48, 32), dim3(256), 0, stream>>>(hidden, w_qkv, b_qkv, cosT,
                                                   sinT, Qw, Kw, Vt);
  attn<<<dim3(16, 32), dim3(256), 0, stream>>>(Qw, Kw, Vt, ctx);
  dense_gemm<<<dim3(16, 32), dim3(256), 0, stream>>>(ctx, w_dense, out);
  copy_bias<<<dim3(8), dim3(256), 0, stream>>>(b_dense, out);
}